// Round 1
// baseline (358.071 us; speedup 1.0000x reference)
//
#include <hip/hip_runtime.h>
#include <hip/hip_bf16.h>

// Problem constants (match reference setup_inputs)
#define NN 30000      // nodes
#define NE 600000     // edges
#define DD 128        // feature dim
#define RR 7          // relations
#define GG 16         // graphs
#define LL 3          // layers

#define NB64 ((NN + 63) / 64)   // 469 buckets of 64 nodes

typedef short bf16x8 __attribute__((ext_vector_type(8)));  // 8 bf16 = 4 VGPRs
typedef float f32x4  __attribute__((ext_vector_type(4)));

// ---- bf16 helpers ----------------------------------------------------------
__device__ __forceinline__ unsigned short f2bf(float f) {
    unsigned u = __float_as_uint(f);
    unsigned r = (u + 0x7fffu + ((u >> 16) & 1u)) >> 16;   // round-nearest-even
    return (unsigned short)r;
}
__device__ __forceinline__ float bf2f(unsigned short b) {
    return __uint_as_float(((unsigned)b) << 16);
}
// packed f32x2 -> bf16x2 (v_cvt_pk_bf16_f32 on gfx950)
__device__ __forceinline__ ushort2 pk2bf(float a, float b) {
    __hip_bfloat162 t = __float22bfloat162_rn(make_float2(a, b));
    return *(ushort2*)&t;
}

// async global->LDS, 16B per lane; LDS dest = wave-uniform base + lane*16
__device__ __forceinline__ void gl_lds16(const void* g, void* l) {
    __builtin_amdgcn_global_load_lds(
        (const __attribute__((address_space(1))) void*)g,
        (__attribute__((address_space(3))) void*)l, 16, 0, 0);
}

// ---------------------------------------------------------------------------
// Weight pack for the fused K=1024 GEMM:
//   B'[kk][c], kk in [0,1024) = [Wl (128 rows) ; Wr (896 rows)], c in [0,128)
// stored per (layer, K-chunk of 128) contiguous, c-major within chunk:
//   Bw2[l][ch][c][kkin] = B'[ch*128+kkin][c]
// ---------------------------------------------------------------------------
__global__ __launch_bounds__(256) void pack_weights(
    const float* __restrict__ Wl,   // L x 128 x 128   (Wl[l][k][c])
    const float* __restrict__ Wr,   // L x 896 x 128   (Wr[l][q][c])
    unsigned short* __restrict__ Bw2)// L x 8 x 128 x 128
{
    int t = blockIdx.x * 256 + threadIdx.x;
    if (t >= LL * 131072) return;
    int l    = t >> 17;
    int rem  = t & 131071;
    int ch   = rem >> 14;          // 0..7 (K-chunk)
    int c    = (rem >> 7) & 127;   // output col
    int kkin = rem & 127;          // K within chunk
    float v;
    if (ch == 0) {
        v = Wl[(size_t)l * 16384 + kkin * 128 + c];
    } else {
        v = Wr[(size_t)l * 114688 + (size_t)((ch - 1) * 128 + kkin) * 128 + c];
    }
    Bw2[t] = f2bf(v);
}

// x (fp32) -> bf16
__global__ __launch_bounds__(256) void convert_bf16(
    const float* __restrict__ in, unsigned short* __restrict__ out, int n4)
{
    int i = blockIdx.x * 256 + threadIdx.x;
    if (i >= n4) return;
    float4 v = ((const float4*)in)[i];
    ushort2 lo = pk2bf(v.x, v.y);
    ushort2 hi = pk2bf(v.z, v.w);
    ((ushort4*)out)[i] = make_ushort4(lo.x, lo.y, hi.x, hi.y);
}

// ---------------------------------------------------------------------------
// Bucketed edge sort (2 passes). Buckets of 64 consecutive out-nodes.
// Counters padded to 64 B to avoid same-line atomic serialization.
// ---------------------------------------------------------------------------
__global__ __launch_bounds__(256) void bucket_hist(
    const int* __restrict__ node_out, int* __restrict__ bcnt, int E)
{
    int e = blockIdx.x * 256 + threadIdx.x;
    if (e < E) atomicAdd(&bcnt[(node_out[e] >> 6) * 16], 1);
}

// Exclusive scan of 469 bucket counts (single block, 512 threads).
__global__ __launch_bounds__(512) void bucket_scan(
    const int* __restrict__ bcnt, int* __restrict__ bstart,
    int* __restrict__ bcur, int nb)
{
    __shared__ int s[512];
    int t = threadIdx.x;
    int v = (t < nb) ? bcnt[t * 16] : 0;
    s[t] = v;
    __syncthreads();
#pragma unroll
    for (int off = 1; off < 512; off <<= 1) {
        int u = (t >= off) ? s[t - off] : 0;
        __syncthreads();
        s[t] += u;
        __syncthreads();
    }
    if (t <= nb) {
        int excl = s[t] - v;                 // for t==nb: v==0 -> total
        bstart[t] = excl;
        if (t < nb) bcur[t * 16] = excl;
    }
}

// Pass A: append edges to their bucket (packed payload).
// pack.x = (out&63)<<18 | in<<3 | rel   (in<30000 -> in*8+rel < 2^18)
__global__ __launch_bounds__(256) void bucket_scatter(
    const int* __restrict__ node_in,
    const int* __restrict__ node_out,
    const int* __restrict__ relation,
    const float* __restrict__ ew,
    int* __restrict__ bcur,
    int2* __restrict__ tmp,
    int E)
{
    int e = blockIdx.x * 256 + threadIdx.x;
    if (e >= E) return;
    int o = node_out[e];
    int pos = atomicAdd(&bcur[(o >> 6) * 16], 1);
    tmp[pos] = make_int2(((o & 63) << 18) | (node_in[e] << 3) | relation[e],
                         __float_as_int(ew[e]));
}

// Pass B: one block per bucket. LDS counting sort over the 64 local nodes;
// emits meta (in<<3|rel, w) in node order AND the global start[] array.
__global__ __launch_bounds__(256) void bucket_sort(
    const int2* __restrict__ tmp,
    const int* __restrict__ bstart,
    int2* __restrict__ meta,
    int* __restrict__ start,
    int N)
{
    __shared__ int hist[64];
    __shared__ int scan[64];
    __shared__ int cur[64];
    const int b = blockIdx.x;
    const int t = threadIdx.x;
    const int s0 = bstart[b];
    const int s1 = bstart[b + 1];

    if (t < 64) hist[t] = 0;
    __syncthreads();
    for (int i = s0 + t; i < s1; i += 256)
        atomicAdd(&hist[((unsigned)tmp[i].x) >> 18], 1);
    __syncthreads();

    int v = (t < 64) ? hist[t] : 0;
    if (t < 64) scan[t] = v;
    __syncthreads();
#pragma unroll
    for (int off = 1; off < 64; off <<= 1) {
        int u = (t < 64 && t >= off) ? scan[t - off] : 0;
        __syncthreads();
        if (t < 64) scan[t] += u;
        __syncthreads();
    }
    if (t < 64) {
        int excl = scan[t] - v;
        cur[t] = s0 + excl;
        int node = b * 64 + t;
        if (node <= N) start[node] = s0 + excl;   // node==N -> start[N]=E
    }
    __syncthreads();

    for (int i = s0 + t; i < s1; i += 256) {
        int2 m = tmp[i];
        int j = ((unsigned)m.x) >> 18;
        int pos = atomicAdd(&cur[j], 1);
        meta[pos] = make_int2(m.x & 0x3ffff, m.y);   // (in<<3)|rel , weight
    }
}

// ---------------------------------------------------------------------------
// aggregate_h: reference-order message aggregation in h-space.
//   upd[n][r*128+c] = sum_{e: out=n, rel=r} w_e * h[in_e][c]     (bf16 out)
// One 64-lane wave per out-node; lane owns 2 columns. Gather source is h
// (7.68 MB, L2/L3-resident) instead of Z (53.76 MB). rel is wave-uniform per
// edge (meta is a broadcast load) -> scalar switch into static accumulators.
// ---------------------------------------------------------------------------
__global__ __launch_bounds__(256) void aggregate_h(
    const unsigned short* __restrict__ hb,   // N x 128 bf16
    const int* __restrict__ start,           // N+1
    const int2* __restrict__ meta,           // E: x=(in<<3)|rel, y=w bits
    unsigned short* __restrict__ upd,        // N x 896 bf16
    int N)
{
    int wid = (blockIdx.x * 256 + threadIdx.x) >> 6;
    int lane = threadIdx.x & 63;
    if (wid >= N) return;

    int e0 = start[wid];
    int e1 = start[wid + 1];

    float ax[7], ay[7];
#pragma unroll
    for (int r = 0; r < 7; ++r) { ax[r] = 0.f; ay[r] = 0.f; }

#define GATHER(m) (*(const unsigned*)(hb + (((size_t)((m).x >> 3)) << 7) + lane * 2))
#define ACCUM(m, u) do {                                                       \
    float w_  = __int_as_float((m).y);                                         \
    float hx_ = __uint_as_float((u) << 16);                                    \
    float hy_ = __uint_as_float((u) & 0xffff0000u);                            \
    switch (__builtin_amdgcn_readfirstlane((m).x) & 7) {                       \
      case 0: ax[0]=fmaf(w_,hx_,ax[0]); ay[0]=fmaf(w_,hy_,ay[0]); break;       \
      case 1: ax[1]=fmaf(w_,hx_,ax[1]); ay[1]=fmaf(w_,hy_,ay[1]); break;       \
      case 2: ax[2]=fmaf(w_,hx_,ax[2]); ay[2]=fmaf(w_,hy_,ay[2]); break;       \
      case 3: ax[3]=fmaf(w_,hx_,ax[3]); ay[3]=fmaf(w_,hy_,ay[3]); break;       \
      case 4: ax[4]=fmaf(w_,hx_,ax[4]); ay[4]=fmaf(w_,hy_,ay[4]); break;       \
      case 5: ax[5]=fmaf(w_,hx_,ax[5]); ay[5]=fmaf(w_,hy_,ay[5]); break;       \
      default: ax[6]=fmaf(w_,hx_,ax[6]); ay[6]=fmaf(w_,hy_,ay[6]); break;      \
    } } while (0)

    int e = e0;
    for (; e + 4 <= e1; e += 4) {
        int2 m0 = meta[e + 0], m1 = meta[e + 1];
        int2 m2 = meta[e + 2], m3 = meta[e + 3];
        unsigned u0 = GATHER(m0), u1 = GATHER(m1);
        unsigned u2 = GATHER(m2), u3 = GATHER(m3);
        ACCUM(m0, u0); ACCUM(m1, u1); ACCUM(m2, u2); ACCUM(m3, u3);
    }
    for (; e < e1; ++e) {
        int2 m = meta[e];
        unsigned u = GATHER(m);
        ACCUM(m, u);
    }
#undef GATHER
#undef ACCUM

    unsigned short* urow = upd + (size_t)wid * 896 + lane * 2;
#pragma unroll
    for (int r = 0; r < 7; ++r) {
        ushort2 p = pk2bf(ax[r], ay[r]);
        *(unsigned*)(urow + r * 128) = ((unsigned)p.y << 16) | p.x;
    }
}

// ---------------------------------------------------------------------------
// Fused GEMM: h_next = relu( [h | upd] (N x 1024) @ B' (1024 x 128) + br+bl )
// Block: 64 rows x 128 cols, 256 threads = 4 waves; K looped in 8 chunks of
// 128 staged via global_load_lds width=16. LDS slot-XOR swizzle (slot^=row&7)
// applied on the GLOBAL source side (linear LDS dest) and on ds_read side ->
// conflict-free b128 service (8-cyc minimum) instead of 16-banks-only (2x).
// A is streamed exactly once; no Zb, no haccb.
// ---------------------------------------------------------------------------
__global__ __launch_bounds__(256) void gemm_fused(
    const unsigned short* __restrict__ hb,    // N x 128 bf16   (K 0..127)
    const unsigned short* __restrict__ upd,   // N x 896 bf16   (K 128..1023)
    const unsigned short* __restrict__ Bw2,   // 8 x 128 x 128 bf16 (per layer)
    const float* __restrict__ br,             // 128
    const float* __restrict__ bl,             // 128
    unsigned short* __restrict__ hout,        // N x 128 bf16 or null
    float* __restrict__ nf,                   // N x 128 f32  or null
    int N)
{
    __shared__ unsigned short As[64 * 128];   // 16 KB
    __shared__ unsigned short Bs[128 * 128];  // 32 KB

    const int tid  = threadIdx.x;
    const int wave = tid >> 6;
    const int lane = tid & 63;
    const int quad = lane >> 4;
    const int l16  = lane & 15;
    const int row0 = blockIdx.x * 64;

    const int lr = lane >> 4;      // sub-row within a 4-row staging group
    const int ls = lane & 15;      // 16B slot within a 256B row

    f32x4 acc[4][2];
#pragma unroll
    for (int mt = 0; mt < 4; ++mt)
#pragma unroll
        for (int nt = 0; nt < 2; ++nt)
            acc[mt][nt] = (f32x4){0.f, 0.f, 0.f, 0.f};

    const unsigned short* As_l = As + l16 * 128;
    const unsigned short* Bs_l = Bs + (wave * 32 + l16) * 128;
    const int swz = l16 & 7;

    for (int ch = 0; ch < 8; ++ch) {
        // ---- stage A (16 KB, 16 wave-issues) with source-side swizzle ----
#pragma unroll
        for (int i = 0; i < 4; ++i) {
            int g = i * 4 + wave;                // 0..15
            int r = g * 4 + lr;                  // LDS row 0..63
            int slot = ls ^ (r & 7);
            const unsigned short* src;
            if (ch == 0)
                src = hb + (size_t)(row0 + r) * 128 + slot * 8;
            else
                src = upd + (size_t)(row0 + r) * 896 + (ch - 1) * 128 + slot * 8;
            gl_lds16(src, As + g * 512);
        }
        // ---- stage B (32 KB, 32 wave-issues), chunk is contiguous ----
        const unsigned short* Bchunk = Bw2 + (size_t)ch * 16384;
#pragma unroll
        for (int i = 0; i < 8; ++i) {
            int g = i * 4 + wave;                // 0..31
            int r = g * 4 + lr;                  // LDS row (=out col) 0..127
            int slot = ls ^ (r & 7);
            gl_lds16(Bchunk + (size_t)r * 128 + slot * 8, Bs + g * 512);
        }
        __syncthreads();

        // ---- compute chunk: 32 MFMA / wave ----
#pragma unroll
        for (int kc = 0; kc < 4; ++kc) {
            int so = ((kc * 4 + quad) ^ swz) * 8;   // swizzled ushort offset
            bf16x8 a0 = *(const bf16x8*)(As_l + 0 * 16 * 128 + so);
            bf16x8 a1 = *(const bf16x8*)(As_l + 1 * 16 * 128 + so);
            bf16x8 a2 = *(const bf16x8*)(As_l + 2 * 16 * 128 + so);
            bf16x8 a3 = *(const bf16x8*)(As_l + 3 * 16 * 128 + so);
            bf16x8 b0 = *(const bf16x8*)(Bs_l + 0 * 16 * 128 + so);
            bf16x8 b1 = *(const bf16x8*)(Bs_l + 1 * 16 * 128 + so);
            acc[0][0] = __builtin_amdgcn_mfma_f32_16x16x32_bf16(a0, b0, acc[0][0], 0, 0, 0);
            acc[1][0] = __builtin_amdgcn_mfma_f32_16x16x32_bf16(a1, b0, acc[1][0], 0, 0, 0);
            acc[2][0] = __builtin_amdgcn_mfma_f32_16x16x32_bf16(a2, b0, acc[2][0], 0, 0, 0);
            acc[3][0] = __builtin_amdgcn_mfma_f32_16x16x32_bf16(a3, b0, acc[3][0], 0, 0, 0);
            acc[0][1] = __builtin_amdgcn_mfma_f32_16x16x32_bf16(a0, b1, acc[0][1], 0, 0, 0);
            acc[1][1] = __builtin_amdgcn_mfma_f32_16x16x32_bf16(a1, b1, acc[1][1], 0, 0, 0);
            acc[2][1] = __builtin_amdgcn_mfma_f32_16x16x32_bf16(a2, b1, acc[2][1], 0, 0, 0);
            acc[3][1] = __builtin_amdgcn_mfma_f32_16x16x32_bf16(a3, b1, acc[3][1], 0, 0, 0);
        }
        __syncthreads();
    }

    // ---- epilogue: bias + relu, write bf16 h_next and/or f32 nf ----
    const int ncol = wave * 32 + l16;        // 0..127 (and +16 for nt=1)
    float bias0 = br[ncol] + bl[ncol];
    float bias1 = br[ncol + 16] + bl[ncol + 16];
#pragma unroll
    for (int mt = 0; mt < 4; ++mt) {
#pragma unroll
        for (int reg = 0; reg < 4; ++reg) {
            int row = row0 + mt * 16 + quad * 4 + reg;
            if (row < N) {
                float v0 = fmaxf(acc[mt][0][reg] + bias0, 0.f);
                float v1 = fmaxf(acc[mt][1][reg] + bias1, 0.f);
                if (hout) {
                    ushort2 p = pk2bf(v0, v1);
                    hout[(size_t)row * DD + ncol]      = p.x;
                    hout[(size_t)row * DD + ncol + 16] = p.y;
                }
                if (nf) {
                    nf[(size_t)row * DD + ncol]      = v0;
                    nf[(size_t)row * DD + ncol + 16] = v1;
                }
            }
        }
    }
}

// ---------------------------------------------------------------------------
// Graph segment sum: gf[n2g[n]] += nf[n] (n2g sorted).
// ---------------------------------------------------------------------------
__global__ __launch_bounds__(256) void graph_sum(
    const float* __restrict__ nf,
    const int* __restrict__ n2g,
    float* __restrict__ gf,
    int N)
{
    int t = blockIdx.x * 256 + threadIdx.x;
    int chunk = t >> 5;
    int lane = t & 31;
    int n0 = chunk * 16;
    if (n0 >= N) return;
    int nend = n0 + 16; if (nend > N) nend = N;

    float4 acc = make_float4(0.f, 0.f, 0.f, 0.f);
    int curg = n2g[n0];
    for (int n = n0; n < nend; ++n) {
        int g = n2g[n];
        if (g != curg) {
            float* dst = gf + (size_t)curg * DD + lane * 4;
            atomicAdd(dst + 0, acc.x); atomicAdd(dst + 1, acc.y);
            atomicAdd(dst + 2, acc.z); atomicAdd(dst + 3, acc.w);
            acc = make_float4(0.f, 0.f, 0.f, 0.f);
            curg = g;
        }
        float4 v = *(const float4*)(nf + (size_t)n * DD + lane * 4);
        acc.x += v.x; acc.y += v.y; acc.z += v.z; acc.w += v.w;
    }
    float* dst = gf + (size_t)curg * DD + lane * 4;
    atomicAdd(dst + 0, acc.x); atomicAdd(dst + 1, acc.y);
    atomicAdd(dst + 2, acc.z); atomicAdd(dst + 3, acc.w);
}

// ---------------------------------------------------------------------------
extern "C" void kernel_launch(void* const* d_in, const int* in_sizes, int n_in,
                              void* d_out, int out_size, void* d_ws, size_t ws_size,
                              hipStream_t stream)
{
    const float* x        = (const float*)d_in[0];
    const int*   node_in  = (const int*)d_in[1];
    const int*   node_out = (const int*)d_in[2];
    const int*   relation = (const int*)d_in[3];
    const float* ew       = (const float*)d_in[4];
    const int*   n2g      = (const int*)d_in[5];
    const float* Wr       = (const float*)d_in[6];
    const float* br       = (const float*)d_in[7];
    const float* Wl       = (const float*)d_in[8];
    const float* bl       = (const float*)d_in[9];

    float* out = (float*)d_out;
    float* gf = out;                 // 16 x 128
    float* nf = out + GG * DD;       // 30000 x 128

    // Workspace layout (~80 MB). Order matters: GEMM A-staging overruns by up
    // to 16 rows past N; each buffer's overrun lands in the next one (safe,
    // outputs row-masked).
    char* w = (char*)d_ws;
    unsigned short* upd  = (unsigned short*)w; w += (size_t)NN * RR * DD * 2;   // 53.76 MB
    unsigned short* hbA  = (unsigned short*)w; w += (size_t)NN * DD * 2;        // 7.68 MB
    unsigned short* hbB  = (unsigned short*)w; w += (size_t)NN * DD * 2;        // 7.68 MB
    unsigned short* Bw2  = (unsigned short*)w; w += (size_t)LL * 131072 * 2;    // 0.79 MB
    int2*  meta   = (int2*)w;                  w += (size_t)NE * 8;             // 4.8 MB
    int2*  tmp    = (int2*)w;                  w += (size_t)NE * 8;             // 4.8 MB
    int*   start  = (int*)w;                   w += (size_t)(NN + 1) * 4 + 60;
    int*   bcnt   = (int*)w;                   w += (size_t)NB64 * 16 * 4 + 64;
    int*   bcur   = (int*)w;                   w += (size_t)NB64 * 16 * 4 + 64;
    int*   bstart = (int*)w;                   w += (size_t)(NB64 + 1) * 4 + 60;

    const int N = NN, E = NE;

    // ---- once per call: weight pack, x->bf16, bucketed edge sort -----------
    pack_weights<<<(LL * 131072 + 255) / 256, 256, 0, stream>>>(Wl, Wr, Bw2);
    convert_bf16<<<(N * DD / 4 + 255) / 256, 256, 0, stream>>>(x, hbA, N * DD / 4);

    hipMemsetAsync(bcnt, 0, (size_t)NB64 * 16 * sizeof(int), stream);
    bucket_hist<<<(E + 255) / 256, 256, 0, stream>>>(node_out, bcnt, E);
    bucket_scan<<<1, 512, 0, stream>>>(bcnt, bstart, bcur, NB64);
    bucket_scatter<<<(E + 255) / 256, 256, 0, stream>>>(
        node_in, node_out, relation, ew, bcur, tmp, E);
    bucket_sort<<<NB64, 256, 0, stream>>>(tmp, bstart, meta, start, N);

    // ---- layers: aggregate in h-space, then fused K=1024 GEMM ----
    unsigned short* hin = hbA;
    unsigned short* hnext = hbB;
    for (int l = 0; l < LL; ++l) {
        const float* br_l = br + (size_t)l * DD;
        const float* bl_l = bl + (size_t)l * DD;
        const unsigned short* Bw2_l = Bw2 + (size_t)l * 131072;
        bool last = (l == LL - 1);

        aggregate_h<<<(N * 64 + 255) / 256, 256, 0, stream>>>(
            hin, start, meta, upd, N);

        gemm_fused<<<(N + 63) / 64, 256, 0, stream>>>(
            hin, upd, Bw2_l, br_l, bl_l,
            last ? (unsigned short*)nullptr : hnext,
            last ? nf : (float*)nullptr, N);

        unsigned short* t = hin; hin = hnext; hnext = t;
    }

    // ---- graph_feature ----
    hipMemsetAsync(gf, 0, (size_t)GG * DD * sizeof(float), stream);
    int chunks = (N + 15) / 16;
    graph_sum<<<(chunks * 32 + 255) / 256, 256, 0, stream>>>(nf, n2g, gf, N);
}

// Round 2
// 329.498 us; speedup vs baseline: 1.0867x; 1.0867x over previous
//
#include <hip/hip_runtime.h>
#include <hip/hip_bf16.h>

// Problem constants (match reference setup_inputs)
#define NN 30000      // nodes
#define NE 600000     // edges
#define DD 128        // feature dim
#define RR 7          // relations
#define GG 16         // graphs
#define LL 3          // layers

#define NB64 ((NN + 63) / 64)   // 469 buckets of 64 nodes

typedef short bf16x8 __attribute__((ext_vector_type(8)));  // 8 bf16 = 4 VGPRs
typedef float f32x4  __attribute__((ext_vector_type(4)));

// ---- bf16 helpers ----------------------------------------------------------
__device__ __forceinline__ unsigned short f2bf(float f) {
    unsigned u = __float_as_uint(f);
    unsigned r = (u + 0x7fffu + ((u >> 16) & 1u)) >> 16;   // round-nearest-even
    return (unsigned short)r;
}
__device__ __forceinline__ float bf2f(unsigned short b) {
    return __uint_as_float(((unsigned)b) << 16);
}
// packed f32x2 -> bf16x2 (v_cvt_pk_bf16_f32 on gfx950)
__device__ __forceinline__ ushort2 pk2bf(float a, float b) {
    __hip_bfloat162 t = __float22bfloat162_rn(make_float2(a, b));
    return *(ushort2*)&t;
}

// async global->LDS, 16B per lane; LDS dest = wave-uniform base + lane*16
__device__ __forceinline__ void gl_lds16(const void* g, void* l) {
    __builtin_amdgcn_global_load_lds(
        (const __attribute__((address_space(1))) void*)g,
        (__attribute__((address_space(3))) void*)l, 16, 0, 0);
}

// ---------------------------------------------------------------------------
// Weight pack: Bw[l][n][k] (bf16, n-major, k contiguous) from fp32
//   n < 128          : Wl[l][k][n]           (h @ Wl part)
//   n = 128 + r*128+c: Wr[l][r*128+k][c]     (upd @ Wr part)
// ---------------------------------------------------------------------------
__global__ __launch_bounds__(256) void pack_weights(
    const float* __restrict__ Wl,   // L x 128 x 128
    const float* __restrict__ Wr,   // L x 896 x 128
    unsigned short* __restrict__ Bw)// L x 1024 x 128
{
    int t = blockIdx.x * 256 + threadIdx.x;
    if (t >= LL * 1024 * DD) return;
    int l = t >> 17;
    int rem = t & 131071;
    int n = rem >> 7;
    int k = rem & 127;
    float v;
    if (n < DD) {
        v = Wl[(size_t)l * DD * DD + k * DD + n];
    } else {
        int q = n - DD;
        v = Wr[(size_t)l * RR * DD * DD + (size_t)((q >> 7) * DD + k) * DD + (q & 127)];
    }
    Bw[(size_t)l * 1024 * DD + n * DD + k] = f2bf(v);
}

// x (fp32) -> bf16
__global__ __launch_bounds__(256) void convert_bf16(
    const float* __restrict__ in, unsigned short* __restrict__ out, int n4)
{
    int i = blockIdx.x * 256 + threadIdx.x;
    if (i >= n4) return;
    float4 v = ((const float4*)in)[i];
    ushort2 lo = pk2bf(v.x, v.y);
    ushort2 hi = pk2bf(v.z, v.w);
    ((ushort4*)out)[i] = make_ushort4(lo.x, lo.y, hi.x, hi.y);
}

// ---------------------------------------------------------------------------
// Bucketed edge sort (2 passes). Buckets of 64 consecutive out-nodes.
// ---------------------------------------------------------------------------
__global__ __launch_bounds__(256) void bucket_hist(
    const int* __restrict__ node_out, int* __restrict__ bcnt, int E)
{
    int e = blockIdx.x * 256 + threadIdx.x;
    if (e < E) atomicAdd(&bcnt[(node_out[e] >> 6) * 16], 1);
}

__global__ __launch_bounds__(512) void bucket_scan(
    const int* __restrict__ bcnt, int* __restrict__ bstart,
    int* __restrict__ bcur, int nb)
{
    __shared__ int s[512];
    int t = threadIdx.x;
    int v = (t < nb) ? bcnt[t * 16] : 0;
    s[t] = v;
    __syncthreads();
#pragma unroll
    for (int off = 1; off < 512; off <<= 1) {
        int u = (t >= off) ? s[t - off] : 0;
        __syncthreads();
        s[t] += u;
        __syncthreads();
    }
    if (t <= nb) {
        int excl = s[t] - v;                 // for t==nb: v==0 -> total
        bstart[t] = excl;
        if (t < nb) bcur[t * 16] = excl;
    }
}

// pack.x = (out&63)<<18 | in<<3 | rel
__global__ __launch_bounds__(256) void bucket_scatter(
    const int* __restrict__ node_in,
    const int* __restrict__ node_out,
    const int* __restrict__ relation,
    const float* __restrict__ ew,
    int* __restrict__ bcur,
    int2* __restrict__ tmp,
    int E)
{
    int e = blockIdx.x * 256 + threadIdx.x;
    if (e >= E) return;
    int o = node_out[e];
    int pos = atomicAdd(&bcur[(o >> 6) * 16], 1);
    tmp[pos] = make_int2(((o & 63) << 18) | (node_in[e] << 3) | relation[e],
                         __float_as_int(ew[e]));
}

// One block per bucket: LDS counting sort over 64 local nodes; emits meta
// (zoff = (in*7+rel)<<7, w) in node order AND the global start[] array.
__global__ __launch_bounds__(256) void bucket_sort(
    const int2* __restrict__ tmp,
    const int* __restrict__ bstart,
    int2* __restrict__ meta,
    int* __restrict__ start,
    int N)
{
    __shared__ int hist[64];
    __shared__ int scan[64];
    __shared__ int cur[64];
    const int b = blockIdx.x;
    const int t = threadIdx.x;
    const int s0 = bstart[b];
    const int s1 = bstart[b + 1];

    if (t < 64) hist[t] = 0;
    __syncthreads();
    for (int i = s0 + t; i < s1; i += 256)
        atomicAdd(&hist[((unsigned)tmp[i].x) >> 18], 1);
    __syncthreads();

    int v = (t < 64) ? hist[t] : 0;
    if (t < 64) scan[t] = v;
    __syncthreads();
#pragma unroll
    for (int off = 1; off < 64; off <<= 1) {
        int u = (t < 64 && t >= off) ? scan[t - off] : 0;
        __syncthreads();
        if (t < 64) scan[t] += u;
        __syncthreads();
    }
    if (t < 64) {
        int excl = scan[t] - v;
        cur[t] = s0 + excl;
        int node = b * 64 + t;
        if (node <= N) start[node] = s0 + excl;   // node==N -> start[N]=E
    }
    __syncthreads();

    for (int i = s0 + t; i < s1; i += 256) {
        int2 m = tmp[i];
        int j = ((unsigned)m.x) >> 18;
        int pos = atomicAdd(&cur[j], 1);
        int key = m.x & 0x3ffff;
        int in = key >> 3, rel = key & 7;
        meta[pos] = make_int2((in * RR + rel) << 7, m.y);   // Z element offset
    }
}

// ---------------------------------------------------------------------------
// MFMA GEMM: [haccb | Zb] (N x 1024) = hb (N x 128 bf16) @ Bw (128 x 1024)
// Block: 64 rows x 256 cols, 256 threads = 4 waves (wave owns 64 rows x 64
// cols, acc[4][4]). K=128 single shot. A (16 KB) + B (64 KB) staged via
// global_load_lds w=16 with source-side XOR swizzle (slot ^= row&7); reads
// use the matching swizzled ds_read_b128 -> conflict-free.
// Grid (469, 4): A re-staged 4x (vs 8x before), 2x MFMA per barrier.
//   y=0, waves 0-1 -> haccb cols 0..127 (bias br+bl added)
//   otherwise      -> Zb cols (col0+wave*64-128) ...
// ---------------------------------------------------------------------------
__global__ __launch_bounds__(256) void gemm_mfma(
    const unsigned short* __restrict__ hb,   // N x 128 bf16
    const unsigned short* __restrict__ Bw,   // 1024 x 128 bf16 (n-major)
    const float* __restrict__ br,            // 128
    const float* __restrict__ bl,            // 128
    unsigned short* __restrict__ haccb,      // N x 128 bf16
    unsigned short* __restrict__ Zb,         // N x 896 bf16
    int N)
{
    __shared__ unsigned short As[64 * 128];    // 16 KB
    __shared__ unsigned short Bs[256 * 128];   // 64 KB

    const int tid  = threadIdx.x;
    const int wave = tid >> 6;
    const int lane = tid & 63;
    const int quad = lane >> 4;
    const int l16  = lane & 15;
    const int row0 = blockIdx.x * 64;
    const int col0 = blockIdx.y * 256;

    const int lr = lane >> 4;      // sub-row within a 4-row staging group
    const int ls = lane & 15;      // 16B slot within a 256B row

    // ---- stage A: 16 groups x 4 rows, swizzled source ----
#pragma unroll
    for (int i = 0; i < 4; ++i) {
        int g = i * 4 + wave;                // 0..15
        int r = g * 4 + lr;                  // 0..63
        int slot = ls ^ (r & 7);
        gl_lds16(hb + (size_t)(row0 + r) * 128 + slot * 8, As + g * 512);
    }
    // ---- stage B: 64 groups x 4 rows (256 n-rows), swizzled source ----
#pragma unroll
    for (int i = 0; i < 16; ++i) {
        int g = i * 4 + wave;                // 0..63
        int r = g * 4 + lr;                  // 0..255
        int slot = ls ^ (r & 7);
        gl_lds16(Bw + (size_t)(col0 + r) * 128 + slot * 8, Bs + g * 512);
    }
    __syncthreads();

    f32x4 acc[4][4];
#pragma unroll
    for (int mt = 0; mt < 4; ++mt)
#pragma unroll
        for (int nt = 0; nt < 4; ++nt)
            acc[mt][nt] = (f32x4){0.f, 0.f, 0.f, 0.f};

    const unsigned short* As_l = As + l16 * 128;
    const unsigned short* Bs_l = Bs + (wave * 64 + l16) * 128;
    const int swz = l16 & 7;

#pragma unroll
    for (int kc = 0; kc < 4; ++kc) {
        int so = ((kc * 4 + quad) ^ swz) * 8;   // swizzled ushort offset
        bf16x8 a0 = *(const bf16x8*)(As_l + 0 * 16 * 128 + so);
        bf16x8 a1 = *(const bf16x8*)(As_l + 1 * 16 * 128 + so);
        bf16x8 a2 = *(const bf16x8*)(As_l + 2 * 16 * 128 + so);
        bf16x8 a3 = *(const bf16x8*)(As_l + 3 * 16 * 128 + so);
        bf16x8 b0 = *(const bf16x8*)(Bs_l + 0 * 16 * 128 + so);
        bf16x8 b1 = *(const bf16x8*)(Bs_l + 1 * 16 * 128 + so);
        bf16x8 b2 = *(const bf16x8*)(Bs_l + 2 * 16 * 128 + so);
        bf16x8 b3 = *(const bf16x8*)(Bs_l + 3 * 16 * 128 + so);
#pragma unroll
        for (int mt = 0; mt < 4; ++mt) {
            bf16x8 a = (mt == 0) ? a0 : (mt == 1) ? a1 : (mt == 2) ? a2 : a3;
            acc[mt][0] = __builtin_amdgcn_mfma_f32_16x16x32_bf16(a, b0, acc[mt][0], 0, 0, 0);
            acc[mt][1] = __builtin_amdgcn_mfma_f32_16x16x32_bf16(a, b1, acc[mt][1], 0, 0, 0);
            acc[mt][2] = __builtin_amdgcn_mfma_f32_16x16x32_bf16(a, b2, acc[mt][2], 0, 0, 0);
            acc[mt][3] = __builtin_amdgcn_mfma_f32_16x16x32_bf16(a, b3, acc[mt][3], 0, 0, 0);
        }
    }

    // ---- epilogue ----
    if (col0 == 0 && wave < 2) {
        // cols wave*64 + nt*16 + l16  (< 128) -> haccb with bias
        float bias[4];
#pragma unroll
        for (int nt = 0; nt < 4; ++nt) {
            int c = wave * 64 + nt * 16 + l16;
            bias[nt] = br[c] + bl[c];
        }
#pragma unroll
        for (int mt = 0; mt < 4; ++mt) {
#pragma unroll
            for (int reg = 0; reg < 4; ++reg) {
                int row = row0 + mt * 16 + quad * 4 + reg;
                if (row < N) {
                    ushort2 p01 = pk2bf(acc[mt][0][reg] + bias[0],
                                        acc[mt][1][reg] + bias[1]);
                    ushort2 p23 = pk2bf(acc[mt][2][reg] + bias[2],
                                        acc[mt][3][reg] + bias[3]);
                    unsigned short* dst = haccb + (size_t)row * 128 + wave * 64 + l16;
                    dst[0]  = p01.x;
                    dst[16] = p01.y;
                    dst[32] = p23.x;
                    dst[48] = p23.y;
                }
            }
        }
    } else {
        const int zc = col0 + wave * 64 - 128;   // >= 0 here
#pragma unroll
        for (int mt = 0; mt < 4; ++mt) {
#pragma unroll
            for (int reg = 0; reg < 4; ++reg) {
                int row = row0 + mt * 16 + quad * 4 + reg;
                if (row < N) {
                    ushort2 p01 = pk2bf(acc[mt][0][reg], acc[mt][1][reg]);
                    ushort2 p23 = pk2bf(acc[mt][2][reg], acc[mt][3][reg]);
                    unsigned short* dst = Zb + (size_t)row * (RR * DD) + zc + l16;
                    dst[0]  = p01.x;
                    dst[16] = p01.y;
                    dst[32] = p23.x;
                    dst[48] = p23.y;
                }
            }
        }
    }
}

// ---------------------------------------------------------------------------
// Aggregate: o[n] = relu(haccb[n] + sum_{e in edges(n)} w_e * Zb[zoff_e][:])
// One 64-lane wave per node, lane owns 2 columns; rel folded into the gather
// address (meta.x = (in*7+rel)*128), single accumulator pair, unroll x8.
// ---------------------------------------------------------------------------
__global__ __launch_bounds__(256) void aggregate(
    const unsigned short* __restrict__ Zb,  // N x 896 bf16
    const int* __restrict__ start,          // N+1
    const int2* __restrict__ meta,          // E
    const unsigned short* __restrict__ haccb, // N x 128 bf16
    float* __restrict__ out_f32,            // N x 128 or null
    unsigned short* __restrict__ out_bf16,  // N x 128 or null
    int N)
{
    int wid = (blockIdx.x * 256 + threadIdx.x) >> 6;
    int lane = threadIdx.x & 63;
    if (wid >= N) return;

    int e0 = start[wid];
    int e1 = start[wid + 1];

    float accx = 0.f, accy = 0.f;
    int e = e0;
    for (; e + 8 <= e1; e += 8) {
        unsigned u[8]; float wt[8];
#pragma unroll
        for (int j = 0; j < 8; ++j) {
            int2 m = meta[e + j];
            u[j] = *(const unsigned*)(Zb + m.x + lane * 2);
            wt[j] = __int_as_float(m.y);
        }
#pragma unroll
        for (int j = 0; j < 8; ++j) {
            accx = fmaf(wt[j], __uint_as_float(u[j] << 16), accx);
            accy = fmaf(wt[j], __uint_as_float(u[j] & 0xffff0000u), accy);
        }
    }
    for (; e + 2 <= e1; e += 2) {
        int2 m0 = meta[e];
        int2 m1 = meta[e + 1];
        unsigned u0 = *(const unsigned*)(Zb + m0.x + lane * 2);
        unsigned u1 = *(const unsigned*)(Zb + m1.x + lane * 2);
        float w0 = __int_as_float(m0.y), w1 = __int_as_float(m1.y);
        accx = fmaf(w0, __uint_as_float(u0 << 16), accx);
        accy = fmaf(w0, __uint_as_float(u0 & 0xffff0000u), accy);
        accx = fmaf(w1, __uint_as_float(u1 << 16), accx);
        accy = fmaf(w1, __uint_as_float(u1 & 0xffff0000u), accy);
    }
    if (e < e1) {
        int2 m = meta[e];
        unsigned u = *(const unsigned*)(Zb + m.x + lane * 2);
        float wt = __int_as_float(m.y);
        accx = fmaf(wt, __uint_as_float(u << 16), accx);
        accy = fmaf(wt, __uint_as_float(u & 0xffff0000u), accy);
    }

    unsigned bu = *(const unsigned*)(haccb + (size_t)wid * DD + lane * 2);
    float ox = fmaxf(bf2f((unsigned short)(bu & 0xffffu)) + accx, 0.f);
    float oy = fmaxf(bf2f((unsigned short)(bu >> 16)) + accy, 0.f);
    if (out_f32) {
        *(float2*)(out_f32 + (size_t)wid * DD + lane * 2) = make_float2(ox, oy);
    }
    if (out_bf16) {
        ushort2 o = pk2bf(ox, oy);
        *(ushort2*)(out_bf16 + (size_t)wid * DD + lane * 2) = o;
    }
}

// ---------------------------------------------------------------------------
// Graph segment sum: gf[n2g[n]] += nf[n] (n2g sorted).
// ---------------------------------------------------------------------------
__global__ __launch_bounds__(256) void graph_sum(
    const float* __restrict__ nf,
    const int* __restrict__ n2g,
    float* __restrict__ gf,
    int N)
{
    int t = blockIdx.x * 256 + threadIdx.x;
    int chunk = t >> 5;
    int lane = t & 31;
    int n0 = chunk * 16;
    if (n0 >= N) return;
    int nend = n0 + 16; if (nend > N) nend = N;

    float4 acc = make_float4(0.f, 0.f, 0.f, 0.f);
    int curg = n2g[n0];
    for (int n = n0; n < nend; ++n) {
        int g = n2g[n];
        if (g != curg) {
            float* dst = gf + (size_t)curg * DD + lane * 4;
            atomicAdd(dst + 0, acc.x); atomicAdd(dst + 1, acc.y);
            atomicAdd(dst + 2, acc.z); atomicAdd(dst + 3, acc.w);
            acc = make_float4(0.f, 0.f, 0.f, 0.f);
            curg = g;
        }
        float4 v = *(const float4*)(nf + (size_t)n * DD + lane * 4);
        acc.x += v.x; acc.y += v.y; acc.z += v.z; acc.w += v.w;
    }
    float* dst = gf + (size_t)curg * DD + lane * 4;
    atomicAdd(dst + 0, acc.x); atomicAdd(dst + 1, acc.y);
    atomicAdd(dst + 2, acc.z); atomicAdd(dst + 3, acc.w);
}

// ---------------------------------------------------------------------------
extern "C" void kernel_launch(void* const* d_in, const int* in_sizes, int n_in,
                              void* d_out, int out_size, void* d_ws, size_t ws_size,
                              hipStream_t stream)
{
    const float* x        = (const float*)d_in[0];
    const int*   node_in  = (const int*)d_in[1];
    const int*   node_out = (const int*)d_in[2];
    const int*   relation = (const int*)d_in[3];
    const float* ew       = (const float*)d_in[4];
    const int*   n2g      = (const int*)d_in[5];
    const float* Wr       = (const float*)d_in[6];
    const float* br       = (const float*)d_in[7];
    const float* Wl       = (const float*)d_in[8];
    const float* bl       = (const float*)d_in[9];

    float* out = (float*)d_out;
    float* gf = out;                 // 16 x 128
    float* nf = out + GG * DD;       // 30000 x 128

    // Workspace layout (~88 MB). GEMM A-staging overruns by up to 16 rows
    // past N; hbA overruns into hbB, hbB into Bw (reads only, outputs masked).
    char* w = (char*)d_ws;
    unsigned short* Zb   = (unsigned short*)w; w += (size_t)NN * RR * DD * 2;   // 53.76 MB
    unsigned short* haccb= (unsigned short*)w; w += (size_t)NN * DD * 2;        // 7.68 MB
    unsigned short* hbA  = (unsigned short*)w; w += (size_t)NN * DD * 2;        // 7.68 MB
    unsigned short* hbB  = (unsigned short*)w; w += (size_t)NN * DD * 2;        // 7.68 MB
    unsigned short* Bw   = (unsigned short*)w; w += (size_t)LL * 1024 * DD * 2; // 0.79 MB
    int2*  meta   = (int2*)w;                  w += (size_t)NE * 8;             // 4.8 MB
    int2*  tmp    = (int2*)w;                  w += (size_t)NE * 8;             // 4.8 MB
    int*   start  = (int*)w;                   w += (size_t)(NN + 1) * 4 + 60;
    int*   bcnt   = (int*)w;                   w += (size_t)NB64 * 16 * 4 + 64;
    int*   bcur   = (int*)w;                   w += (size_t)NB64 * 16 * 4 + 64;
    int*   bstart = (int*)w;                   w += (size_t)(NB64 + 1) * 4 + 60;

    const int N = NN, E = NE;

    // ---- once per call: weight pack, x->bf16, bucketed edge sort -----------
    pack_weights<<<(LL * 1024 * DD + 255) / 256, 256, 0, stream>>>(Wl, Wr, Bw);
    convert_bf16<<<(N * DD / 4 + 255) / 256, 256, 0, stream>>>(x, hbA, N * DD / 4);

    hipMemsetAsync(bcnt, 0, (size_t)NB64 * 16 * sizeof(int), stream);
    bucket_hist<<<(E + 255) / 256, 256, 0, stream>>>(node_out, bcnt, E);
    bucket_scan<<<1, 512, 0, stream>>>(bcnt, bstart, bcur, NB64);
    bucket_scatter<<<(E + 255) / 256, 256, 0, stream>>>(
        node_in, node_out, relation, ew, bcur, tmp, E);
    bucket_sort<<<NB64, 256, 0, stream>>>(tmp, bstart, meta, start, N);

    // ---- layers ----
    dim3 ggrid((N + 63) / 64, 4);
    unsigned short* hin = hbA;
    unsigned short* hnext = hbB;
    for (int l = 0; l < LL; ++l) {
        const float* br_l = br + (size_t)l * DD;
        const float* bl_l = bl + (size_t)l * DD;
        const unsigned short* Bw_l = Bw + (size_t)l * 1024 * DD;

        gemm_mfma<<<ggrid, 256, 0, stream>>>(hin, Bw_l, br_l, bl_l, haccb, Zb, N);

        bool last = (l == LL - 1);
        aggregate<<<(N * 64 + 255) / 256, 256, 0, stream>>>(
            Zb, start, meta, haccb,
            last ? nf : (float*)nullptr,
            last ? (unsigned short*)nullptr : hnext, N);

        unsigned short* t = hin; hin = hnext; hnext = t;
    }

    // ---- graph_feature ----
    hipMemsetAsync(gf, 0, (size_t)GG * DD * sizeof(float), stream);
    int chunks = (N + 15) / 16;
    graph_sum<<<(chunks * 32 + 255) / 256, 256, 0, stream>>>(nf, n2g, gf, N);
}